// Round 1
// baseline (206.121 us; speedup 1.0000x reference)
//
#include <hip/hip_runtime.h>
#include <hip/hip_bf16.h>

#define B_    128
#define N_    196
#define HDIM  512
#define VDIM  2048
#define ATT   512
#define M_TOT (B_ * N_)   // 25088

#define BM  64     // rows per GEMM block
#define BKK 64     // K step
#define BN  128    // ATT cols per GEMM block (4 chunks)
#define LDP 72     // padded LDS row length (bf16 elems): 144B rows, 16B-aligned

typedef float  f32x4  __attribute__((ext_vector_type(4)));
typedef __bf16 bf16x8 __attribute__((ext_vector_type(8)));

// ---------------------------------------------------------------------------
// Kernel T: Uw [VDIM][ATT] f32  ->  UwT [ATT][VDIM] bf16  (tiled transpose)
// ---------------------------------------------------------------------------
__global__ void k_transpose(const float* __restrict__ Uw, __bf16* __restrict__ UwT) {
    __shared__ __bf16 st[64][65];
    int k0 = blockIdx.x * 64;
    int c0 = blockIdx.y * 64;
    int t  = threadIdx.x;  // 256
#pragma unroll
    for (int i = 0; i < 16; ++i) {
        int lin = i * 256 + t;
        int kk = lin >> 6, cc = lin & 63;
        st[kk][cc] = (__bf16)Uw[(size_t)(k0 + kk) * ATT + c0 + cc];
    }
    __syncthreads();
#pragma unroll
    for (int i = 0; i < 16; ++i) {
        int lin = i * 256 + t;
        int cc = lin >> 6, kk = lin & 63;
        UwT[(size_t)(c0 + cc) * VDIM + k0 + kk] = st[kk][cc];
    }
}

// ---------------------------------------------------------------------------
// Kernel W: whp[b][a] = h[b] @ Ww[:,a] + Wb[a] + Ub[a]   (fp32, tiny)
// ---------------------------------------------------------------------------
__global__ void k_wh(const float* __restrict__ h, const float* __restrict__ Ww,
                     const float* __restrict__ Wb, const float* __restrict__ Ub,
                     float* __restrict__ whp) {
    __shared__ float hs[HDIM];
    int b = blockIdx.x;
    int t = threadIdx.x;  // 256
    hs[t]       = h[(size_t)b * HDIM + t];
    hs[t + 256] = h[(size_t)b * HDIM + t + 256];
    __syncthreads();
    float acc0 = 0.f, acc1 = 0.f;
    for (int k = 0; k < HDIM; ++k) {
        float hv = hs[k];
        acc0 += hv * Ww[(size_t)k * ATT + t];
        acc1 += hv * Ww[(size_t)k * ATT + t + 256];
    }
    whp[(size_t)b * ATT + t]       = acc0 + Wb[t] + Ub[t];
    whp[(size_t)b * ATT + t + 256] = acc1 + Wb[t + 256] + Ub[t + 256];
}

// ---------------------------------------------------------------------------
// Kernel G: per (64-row, 128-col) tile: bf16 MFMA GEMM over K=2048,
// then tanh(acc + whp) . vw  -> e_part[cc][m]  (partial over the col chunk)
// ---------------------------------------------------------------------------
__global__ __launch_bounds__(256) void k_scores(
    const float* __restrict__ V, const __bf16* __restrict__ UwT,
    const float* __restrict__ whp, const float* __restrict__ vw,
    float* __restrict__ e_part)
{
    __shared__ __align__(16) __bf16 As[BM][LDP];   // V rows (bf16)
    __shared__ __align__(16) __bf16 Bs[BN][LDP];   // Uw cols (bf16), [col][k]
    __shared__ float red[2][BM];

    int mtile = blockIdx.x;       // 0..391
    int cc    = blockIdx.y;       // 0..3
    int m0 = mtile * BM;
    int c0 = cc * BN;
    int t    = threadIdx.x;
    int lane = t & 63;
    int wave = t >> 6;            // 0..3
    int wr = wave >> 1;           // 0..1 (row half)
    int wc = wave & 1;            // 0..1 (col half)

    f32x4 acc[2][4];
#pragma unroll
    for (int i = 0; i < 2; ++i)
#pragma unroll
        for (int j = 0; j < 4; ++j) acc[i][j] = (f32x4){0.f, 0.f, 0.f, 0.f};

    // staging assignments
    int ra = t >> 2;            // 0..63 : A row
    int ka = (t & 3) * 16;      // 0/16/32/48 : A k offset (16 floats)
    int cb = t >> 1;            // 0..127 : B col
    int kb = (t & 1) * 32;      // 0/32 : B k offset (32 bf16)

    const float*  Arow = V   + (size_t)(m0 + ra) * VDIM + ka;
    const __bf16* Brow = UwT + (size_t)(c0 + cb) * VDIM + kb;

    int lcol  = lane & 15;
    int lgrp8 = (lane >> 4) * 8;

    for (int k0 = 0; k0 < VDIM; k0 += BKK) {
        __syncthreads();
        // stage A: 16 f32 -> 16 bf16 per thread (2x b128 LDS writes)
        {
            const float4* src = reinterpret_cast<const float4*>(Arow + k0);
#pragma unroll
            for (int i = 0; i < 2; ++i) {
                float4 x = src[2 * i];
                float4 y = src[2 * i + 1];
                bf16x8 w;
                w[0] = (__bf16)x.x; w[1] = (__bf16)x.y; w[2] = (__bf16)x.z; w[3] = (__bf16)x.w;
                w[4] = (__bf16)y.x; w[5] = (__bf16)y.y; w[6] = (__bf16)y.z; w[7] = (__bf16)y.w;
                *reinterpret_cast<bf16x8*>(&As[ra][ka + 8 * i]) = w;
            }
        }
        // stage B: 32 bf16 per thread, direct copy (4x 16B)
        {
            const bf16x8* src = reinterpret_cast<const bf16x8*>(Brow + k0);
#pragma unroll
            for (int i = 0; i < 4; ++i)
                *reinterpret_cast<bf16x8*>(&Bs[cb][kb + 8 * i]) = src[i];
        }
        __syncthreads();

        int arow_base = wr * 32;
        int bcol_base = wc * 64;
#pragma unroll
        for (int ks = 0; ks < 2; ++ks) {
            int kofs = ks * 32 + lgrp8;
            bf16x8 af[2], bfr[4];
#pragma unroll
            for (int i = 0; i < 2; ++i)
                af[i] = *reinterpret_cast<const bf16x8*>(&As[arow_base + i * 16 + lcol][kofs]);
#pragma unroll
            for (int j = 0; j < 4; ++j)
                bfr[j] = *reinterpret_cast<const bf16x8*>(&Bs[bcol_base + j * 16 + lcol][kofs]);
#pragma unroll
            for (int i = 0; i < 2; ++i)
#pragma unroll
                for (int j = 0; j < 4; ++j)
                    acc[i][j] = __builtin_amdgcn_mfma_f32_16x16x32_bf16(af[i], bfr[j], acc[i][j], 0, 0, 0);
        }
    }

    // epilogue: x = acc + whp[b][col]; rowsum += tanh(x)*vw[col]; reduce over 16 cols
    int lrow4 = (lane >> 4) * 4;
#pragma unroll
    for (int i = 0; i < 2; ++i) {
        float rowsum[4] = {0.f, 0.f, 0.f, 0.f};
#pragma unroll
        for (int j = 0; j < 4; ++j) {
            int col = c0 + wc * 64 + j * 16 + lcol;
            float vwv = vw[col];
#pragma unroll
            for (int r = 0; r < 4; ++r) {
                int m = m0 + wr * 32 + i * 16 + lrow4 + r;
                int b = m / N_;
                float x = acc[i][j][r] + whp[(size_t)b * ATT + col];
                rowsum[r] += tanhf(x) * vwv;
            }
        }
#pragma unroll
        for (int r = 0; r < 4; ++r) {
            rowsum[r] += __shfl_xor(rowsum[r], 1);
            rowsum[r] += __shfl_xor(rowsum[r], 2);
            rowsum[r] += __shfl_xor(rowsum[r], 4);
            rowsum[r] += __shfl_xor(rowsum[r], 8);
        }
        if (lcol == 0) {
#pragma unroll
            for (int r = 0; r < 4; ++r)
                red[wc][wr * 32 + i * 16 + lrow4 + r] = rowsum[r];
        }
    }
    __syncthreads();
    if (t < BM)
        e_part[(size_t)cc * M_TOT + m0 + t] = red[0][t] + red[1][t];
}

// ---------------------------------------------------------------------------
// Kernel S: softmax over N=196 per batch; writes a -> d_out tail
// ---------------------------------------------------------------------------
__global__ void k_softmax(const float* __restrict__ e_part, const float* __restrict__ vb,
                          float* __restrict__ a_out) {
    int b = blockIdx.x;
    int t = threadIdx.x;  // 256
    __shared__ float sm[256];
    float ev = 0.f;
    float e  = -1e30f;
    if (t < N_) {
        int m = b * N_ + t;
        ev = e_part[m] + e_part[M_TOT + m] + e_part[2 * M_TOT + m] + e_part[3 * M_TOT + m] + vb[0];
        e = ev;
    }
    sm[t] = e;
    __syncthreads();
    for (int s = 128; s > 0; s >>= 1) {
        if (t < s) sm[t] = fmaxf(sm[t], sm[t + s]);
        __syncthreads();
    }
    float mx = sm[0];
    __syncthreads();
    float ex = (t < N_) ? __expf(ev - mx) : 0.f;
    sm[t] = ex;
    __syncthreads();
    for (int s = 128; s > 0; s >>= 1) {
        if (t < s) sm[t] += sm[t + s];
        __syncthreads();
    }
    float inv = 1.f / sm[0];
    if (t < N_) a_out[(size_t)b * N_ + t] = ex * inv;
}

// ---------------------------------------------------------------------------
// Kernel C: ctx[b][v] = sum_n a[b][n] * V[b][n][v]   (streaming, fp32)
// ---------------------------------------------------------------------------
__global__ void k_ctx(const float* __restrict__ V, const float* __restrict__ a,
                      float* __restrict__ ctx) {
    int b  = blockIdx.x;   // 128
    int ch = blockIdx.y;   // 4 chunks of 512 cols
    int t  = threadIdx.x;  // 128
    __shared__ float as_[N_];
    for (int i = t; i < N_; i += 128) as_[i] = a[(size_t)b * N_ + i];
    __syncthreads();
    int col = ch * 512 + t * 4;
    const f32x4* Vp = reinterpret_cast<const f32x4*>(V + (size_t)b * N_ * VDIM + col);
    f32x4 accv = {0.f, 0.f, 0.f, 0.f};
    for (int n = 0; n < N_; ++n)
        accv += as_[n] * Vp[(size_t)n * (VDIM / 4)];
    *reinterpret_cast<f32x4*>(ctx + (size_t)b * VDIM + col) = accv;
}

// ---------------------------------------------------------------------------
extern "C" void kernel_launch(void* const* d_in, const int* in_sizes, int n_in,
                              void* d_out, int out_size, void* d_ws, size_t ws_size,
                              hipStream_t stream) {
    const float* h  = (const float*)d_in[0];
    const float* V  = (const float*)d_in[1];
    const float* Ww = (const float*)d_in[2];
    const float* Wb = (const float*)d_in[3];
    const float* Uw = (const float*)d_in[4];
    const float* Ub = (const float*)d_in[5];
    const float* vw = (const float*)d_in[6];
    const float* vb = (const float*)d_in[7];

    float* out     = (float*)d_out;
    float* ctx_out = out;                        // B*VDIM floats
    float* a_out   = out + (size_t)B_ * VDIM;    // B*N floats

    char* ws = (char*)d_ws;
    __bf16* UwT   = (__bf16*)ws;                                   // 2 MiB
    float*  whp   = (float*)(ws + 2u * 1024 * 1024);               // 256 KiB
    float*  e_prt = (float*)(ws + 2u * 1024 * 1024 + 256 * 1024);  // ~392 KiB

    k_transpose<<<dim3(VDIM / 64, ATT / 64), 256, 0, stream>>>(Uw, UwT);
    k_wh<<<dim3(B_), 256, 0, stream>>>(h, Ww, Wb, Ub, whp);
    k_scores<<<dim3(M_TOT / BM, ATT / BN), 256, 0, stream>>>(V, UwT, whp, vw, e_prt);
    k_softmax<<<dim3(B_), 256, 0, stream>>>(e_prt, vb, a_out);
    k_ctx<<<dim3(B_, 4), 128, 0, stream>>>(V, a_out, ctx_out);
}